// Round 1
// baseline (430.505 us; speedup 1.0000x reference)
//
#include <hip/hip_runtime.h>
#include <hip/hip_bf16.h>
#include <stdint.h>

// Problem constants (from reference):
//   x: [B=16, H=224, W=224, C=64] fp32 (NHWC)
//   gating_kernel: [2,2,64,1] fp32
//   conv stride 2x2, valid -> g: [16, 112, 112]; n = 12544 patches/batch
//   top-K with K=1254 per batch; gate = scatter of top-k values; out = x * gate (broadcast 2x2xC)
#define BATCH   16
#define HDIM    224
#define WDIM    224
#define CDIM    64
#define HO      112
#define WO      112
#define NPATCH  (HO * WO)        // 12544
#define KSEL    1254
#define ROWF    (WDIM * CDIM)    // floats per image row = 14336

// ---------------------------------------------------------------------------
// Kernel 1: gating conv. One patch per half-wave (32 lanes).
// Each patch reads 2 rows x 128 contiguous floats; lane l loads float4 at
// offset l*4 within the 128-float chunk -> 512 B fully coalesced per row.
// Weight layout [dh][dw][c]: chunk position pos = dw*64+c = l*4 exactly, so
// lane weights are wk[l*4 + {0..3}] (dh=0) and wk[128 + l*4 + {0..3}] (dh=1).
// ---------------------------------------------------------------------------
__global__ __launch_bounds__(256) void conv_gate_kernel(
    const float* __restrict__ x, const float* __restrict__ wk,
    float* __restrict__ g) {
  const int tid = threadIdx.x;
  const int lane = tid & 31;                 // lane within half-wave
  const int p = blockIdx.x * 8 + (tid >> 5); // patch id, 8 half-waves/block
  // total patches = 16*12544 = 200704 = 25088 blocks * 8 exactly

  const int b   = p / NPATCH;
  const int rem = p - b * NPATCH;
  const int ho  = rem / WO;
  const int wo  = rem - ho * WO;

  const float4 w0 = *reinterpret_cast<const float4*>(wk + lane * 4);
  const float4 w1 = *reinterpret_cast<const float4*>(wk + 128 + lane * 4);

  const long row0 = (long)(b * HDIM + 2 * ho) * ROWF + wo * 128 + lane * 4;
  const float4 a0 = *reinterpret_cast<const float4*>(x + row0);
  const float4 a1 = *reinterpret_cast<const float4*>(x + row0 + ROWF);

  float partial = a0.x * w0.x + a0.y * w0.y + a0.z * w0.z + a0.w * w0.w
                + a1.x * w1.x + a1.y * w1.y + a1.z * w1.z + a1.w * w1.w;

  // reduce across the 32 lanes of the half-wave
  #pragma unroll
  for (int off = 16; off > 0; off >>= 1)
    partial += __shfl_down(partial, off, 32);

  if (lane == 0) g[p] = partial;
}

// ---------------------------------------------------------------------------
// Kernel 2: exact per-batch top-K selection via 4-round radix select on
// order-preserving uint32 keys, with stable (lowest-index-first) tie handling.
// One block per batch; keys live in LDS (50 KB).
// Writes dense gate[B][NPATCH]: g value if selected else 0.
// ---------------------------------------------------------------------------
__global__ __launch_bounds__(256) void select_kernel(
    const float* __restrict__ g, float* __restrict__ gate) {
  __shared__ uint32_t keys[NPATCH];       // 50176 B
  __shared__ int hist[256];
  __shared__ int sh_krem;
  __shared__ uint32_t sh_prefix;
  __shared__ int eq_list[1024];
  __shared__ int eq_count;

  const int b = blockIdx.x;
  const float* gb   = g    + b * NPATCH;
  float*       gtb  = gate + b * NPATCH;
  const int tid = threadIdx.x;

  for (int i = tid; i < NPATCH; i += 256) {
    uint32_t u = __float_as_uint(gb[i]);
    // monotone map: larger float -> larger uint
    keys[i] = (u & 0x80000000u) ? ~u : (u | 0x80000000u);
  }
  if (tid == 0) { sh_krem = KSEL; sh_prefix = 0u; eq_count = 0; }
  __syncthreads();

  uint32_t mask = 0u;
  #pragma unroll
  for (int r = 3; r >= 0; --r) {
    if (tid < 256) hist[tid] = 0;
    __syncthreads();
    const uint32_t prefix = sh_prefix;
    for (int i = tid; i < NPATCH; i += 256) {
      uint32_t k = keys[i];
      if ((k & mask) == prefix)
        atomicAdd(&hist[(k >> (r * 8)) & 255], 1);
    }
    __syncthreads();
    if (tid == 0) {
      int krem = sh_krem;
      int acc = 0;
      for (int bin = 255; bin >= 0; --bin) {
        int c = hist[bin];
        if (acc + c >= krem) {
          sh_krem = krem - acc;                       // rank within chosen bin
          sh_prefix = prefix | ((uint32_t)bin << (r * 8));
          break;
        }
        acc += c;
      }
    }
    __syncthreads();
    mask |= 0xFFu << (r * 8);
  }

  const uint32_t thresh = sh_prefix;   // exact key of the K-th largest value
  for (int i = tid; i < NPATCH; i += 256) {
    uint32_t k = keys[i];
    if (k > thresh)       gtb[i] = gb[i];
    else if (k < thresh)  gtb[i] = 0.0f;
    else {
      int pos = atomicAdd(&eq_count, 1);
      if (pos < 1024) eq_list[pos] = i;  // gate written below by thread 0
    }
  }
  __syncthreads();

  if (tid == 0) {
    const int krem = sh_krem;            // how many of the equals to keep
    const int ec = eq_count;
    if (ec <= 1024) {
      // tiny list (almost always size == krem == 1): sort ascending by index
      for (int i = 0; i < ec; ++i) {
        int mn = i;
        for (int j = i + 1; j < ec; ++j)
          if (eq_list[j] < eq_list[mn]) mn = j;
        int t = eq_list[mn]; eq_list[mn] = eq_list[i]; eq_list[i] = t;
      }
      for (int i = 0; i < ec; ++i) {
        int idx = eq_list[i];
        gtb[idx] = (i < krem) ? gb[idx] : 0.0f;
      }
    } else {
      // pathological tie fallback: serial index-order scan
      int kept = 0;
      for (int i = 0; i < NPATCH; ++i) {
        if (keys[i] == thresh) {
          gtb[i] = (kept < krem) ? gb[i] : 0.0f;
          ++kept;
        }
      }
    }
  }
}

// ---------------------------------------------------------------------------
// Kernel 3: streaming multiply. One float4 per thread; gate scalar broadcast
// (16 consecutive threads share one gate value -> cache broadcast).
// ---------------------------------------------------------------------------
__global__ __launch_bounds__(256) void apply_gate_kernel(
    const float* __restrict__ x, const float* __restrict__ gate,
    float* __restrict__ out) {
  const long v = (long)blockIdx.x * 256 + threadIdx.x;   // float4 index
  const long pixel = v >> 4;                              // 64 ch = 16 float4
  const int  b   = (int)(pixel / (HDIM * WDIM));
  const int  rem = (int)(pixel - (long)b * (HDIM * WDIM));
  const int  h   = rem / WDIM;
  const int  w   = rem - h * WDIM;
  const int  gidx = b * NPATCH + (h >> 1) * WO + (w >> 1);

  const float gv = gate[gidx];
  const float4 a = *reinterpret_cast<const float4*>(x + v * 4);
  float4 o;
  o.x = a.x * gv; o.y = a.y * gv; o.z = a.z * gv; o.w = a.w * gv;
  *reinterpret_cast<float4*>(out + v * 4) = o;
}

extern "C" void kernel_launch(void* const* d_in, const int* in_sizes, int n_in,
                              void* d_out, int out_size, void* d_ws, size_t ws_size,
                              hipStream_t stream) {
  const float* x  = (const float*)d_in[0];   // [16,224,224,64]
  const float* wk = (const float*)d_in[1];   // [2,2,64,1] = 256 floats
  float* out = (float*)d_out;

  float* g    = (float*)d_ws;                       // [16, 12544]
  float* gate = g + BATCH * NPATCH;                 // [16, 12544]

  // 1) gating conv: 200704 patches, 8 per block
  conv_gate_kernel<<<(BATCH * NPATCH) / 8, 256, 0, stream>>>(x, wk, g);

  // 2) exact top-K selection per batch -> dense gate
  select_kernel<<<BATCH, 256, 0, stream>>>(g, gate);

  // 3) apply gate: 51380224 floats = 12845056 float4 = 50176 blocks x 256
  apply_gate_kernel<<<(long)out_size / 4 / 256, 256, 0, stream>>>(x, gate, out);
}

// Round 2
// 391.897 us; speedup vs baseline: 1.0985x; 1.0985x over previous
//
#include <hip/hip_runtime.h>
#include <hip/hip_bf16.h>
#include <stdint.h>

// Problem constants (from reference):
//   x: [B=16, H=224, W=224, C=64] fp32 (NHWC)
//   gating_kernel: [2,2,64,1] fp32
//   conv stride 2x2, valid -> g: [16, 112, 112]; n = 12544 patches/batch
//   top-K with K=1254 per batch; gate = scatter of top-k values; out = x * gate
#define BATCH   16
#define HDIM    224
#define WDIM    224
#define CDIM    64
#define HO      112
#define WO      112
#define NPATCH  (HO * WO)        // 12544 = 256 * 49
#define KSEL    1254
#define ROWF    (WDIM * CDIM)    // floats per image row = 14336
#define PERTHR  49               // keys per thread in select (12544/256)

// ---------------------------------------------------------------------------
// Kernel 1: gating conv. One patch per half-wave (32 lanes).
// Each patch reads 2 rows x 128 contiguous floats; lane l loads float4 at
// offset l*4 -> 512 B fully coalesced per row. Memory-bound: 205 MB read.
// ---------------------------------------------------------------------------
__global__ __launch_bounds__(256) void conv_gate_kernel(
    const float* __restrict__ x, const float* __restrict__ wk,
    float* __restrict__ g) {
  const int tid = threadIdx.x;
  const int lane = tid & 31;
  const int p = blockIdx.x * 8 + (tid >> 5);  // 8 half-waves/block

  const int b   = p / NPATCH;
  const int rem = p - b * NPATCH;
  const int ho  = rem / WO;
  const int wo  = rem - ho * WO;

  const float4 w0 = *reinterpret_cast<const float4*>(wk + lane * 4);
  const float4 w1 = *reinterpret_cast<const float4*>(wk + 128 + lane * 4);

  const long row0 = (long)(b * HDIM + 2 * ho) * ROWF + wo * 128 + lane * 4;
  const float4 a0 = *reinterpret_cast<const float4*>(x + row0);
  const float4 a1 = *reinterpret_cast<const float4*>(x + row0 + ROWF);

  float partial = a0.x * w0.x + a0.y * w0.y + a0.z * w0.z + a0.w * w0.w
                + a1.x * w1.x + a1.y * w1.y + a1.z * w1.z + a1.w * w1.w;

  #pragma unroll
  for (int off = 16; off > 0; off >>= 1)
    partial += __shfl_down(partial, off, 32);

  if (lane == 0) g[p] = partial;
}

// ---------------------------------------------------------------------------
// Kernel 2: exact per-batch top-K threshold via 32-step bitwise binary search
// on order-preserving uint32 keys. NO histograms, NO LDS atomics (the R0
// version serialized ~12.5k atomicAdds into ~6 hot exponent bins).
// Keys live in registers: 49/thread. Stable lowest-index tie handling.
// ---------------------------------------------------------------------------
__global__ __launch_bounds__(256) void select_kernel(
    const float* __restrict__ g, float* __restrict__ gate) {
  __shared__ int wave_cnt[4];
  __shared__ uint32_t sh_T;
  __shared__ int sh_cg;
  __shared__ int eq_list[256];
  __shared__ int eq_count;

  const int b = blockIdx.x;
  const int tid = threadIdx.x;
  const float* __restrict__ gb  = g    + b * NPATCH;
  float* __restrict__       gtb = gate + b * NPATCH;

  // load keys (coalesced: stride-256 across threads)
  uint32_t key[PERTHR];
  #pragma unroll
  for (int j = 0; j < PERTHR; ++j) {
    uint32_t u = __float_as_uint(gb[tid + j * 256]);
    key[j] = (u & 0x80000000u) ? ~u : (u | 0x80000000u);  // monotone map
  }
  if (tid == 0) eq_count = 0;

  // find T = exact key of the K-th largest value:
  // T = max{t : count(keys >= t) >= K}, built bit by bit from the top.
  uint32_t T = 0;
  for (int bit = 31; bit >= 0; --bit) {
    const uint32_t cand = T | (1u << bit);
    int c = 0;
    #pragma unroll
    for (int j = 0; j < PERTHR; ++j) c += (key[j] >= cand) ? 1 : 0;
    #pragma unroll
    for (int off = 32; off > 0; off >>= 1) c += __shfl_down(c, off, 64);
    if ((tid & 63) == 0) wave_cnt[tid >> 6] = c;
    __syncthreads();
    if (tid == 0) {
      int tot = wave_cnt[0] + wave_cnt[1] + wave_cnt[2] + wave_cnt[3];
      sh_T = (tot >= KSEL) ? cand : T;
    }
    __syncthreads();
    T = sh_T;
  }

  // count strictly-greater to get how many threshold-equal elements to keep
  {
    int c = 0;
    #pragma unroll
    for (int j = 0; j < PERTHR; ++j) c += (key[j] > T) ? 1 : 0;
    #pragma unroll
    for (int off = 32; off > 0; off >>= 1) c += __shfl_down(c, off, 64);
    if ((tid & 63) == 0) wave_cnt[tid >> 6] = c;
    __syncthreads();
    if (tid == 0) sh_cg = wave_cnt[0] + wave_cnt[1] + wave_cnt[2] + wave_cnt[3];
    __syncthreads();
  }
  const int krem = KSEL - sh_cg;  // ties to keep, lowest index first

  // write dense gate; reconstruct float from key (exact inverse of the map)
  #pragma unroll
  for (int j = 0; j < PERTHR; ++j) {
    const int i = tid + j * 256;
    const uint32_t k = key[j];
    float v = 0.0f;
    if (k > T) {
      uint32_t u = (k & 0x80000000u) ? (k & 0x7FFFFFFFu) : ~k;
      v = __uint_as_float(u);
    }
    gtb[i] = v;
    if (k == T) {
      int pos = atomicAdd(&eq_count, 1);
      if (pos < 256) eq_list[pos] = i;
    }
  }
  __syncthreads();

  if (tid == 0) {
    const int ec = eq_count;
    if (ec <= 256) {
      // sort tiny tie list ascending by index (almost always ec == krem == 1)
      for (int i = 0; i < ec; ++i) {
        int mn = i;
        for (int j = i + 1; j < ec; ++j)
          if (eq_list[j] < eq_list[mn]) mn = j;
        int t = eq_list[mn]; eq_list[mn] = eq_list[i]; eq_list[i] = t;
      }
      for (int i = 0; i < ec; ++i) {
        int idx = eq_list[i];
        if (i < krem) {
          uint32_t u = (T & 0x80000000u) ? (T & 0x7FFFFFFFu) : ~T;
          gtb[idx] = __uint_as_float(u);
        }  // else stays 0
      }
    } else {
      // pathological mass-tie fallback: serial index-order rescan
      int kept = 0;
      for (int i = 0; i < NPATCH; ++i) {
        uint32_t u = __float_as_uint(gb[i]);
        uint32_t k = (u & 0x80000000u) ? ~u : (u | 0x80000000u);
        if (k == T) {
          gtb[i] = (kept < krem) ? gb[i] : 0.0f;
          ++kept;
        }
      }
    }
  }
}

// ---------------------------------------------------------------------------
// Kernel 3: streaming multiply. One float4 per thread; gate scalar broadcast
// (16 consecutive threads share one gate value -> same cache line).
// ---------------------------------------------------------------------------
__global__ __launch_bounds__(256) void apply_gate_kernel(
    const float* __restrict__ x, const float* __restrict__ gate,
    float* __restrict__ out) {
  const long v = (long)blockIdx.x * 256 + threadIdx.x;   // float4 index
  const long pixel = v >> 4;                              // 64 ch = 16 float4
  const int  b   = (int)(pixel / (HDIM * WDIM));
  const int  rem = (int)(pixel - (long)b * (HDIM * WDIM));
  const int  h   = rem / WDIM;
  const int  w   = rem - h * WDIM;
  const int  gidx = b * NPATCH + (h >> 1) * WO + (w >> 1);

  const float gv = gate[gidx];
  const float4 a = *reinterpret_cast<const float4*>(x + v * 4);
  float4 o;
  o.x = a.x * gv; o.y = a.y * gv; o.z = a.z * gv; o.w = a.w * gv;
  *reinterpret_cast<float4*>(out + v * 4) = o;
}

extern "C" void kernel_launch(void* const* d_in, const int* in_sizes, int n_in,
                              void* d_out, int out_size, void* d_ws, size_t ws_size,
                              hipStream_t stream) {
  const float* x  = (const float*)d_in[0];   // [16,224,224,64]
  const float* wk = (const float*)d_in[1];   // [2,2,64,1] = 256 floats
  float* out = (float*)d_out;

  float* g    = (float*)d_ws;                // [16, 12544]
  float* gate = g + BATCH * NPATCH;          // [16, 12544]

  conv_gate_kernel<<<(BATCH * NPATCH) / 8, 256, 0, stream>>>(x, wk, g);
  select_kernel<<<BATCH, 256, 0, stream>>>(g, gate);
  apply_gate_kernel<<<(long)out_size / 4 / 256, 256, 0, stream>>>(x, gate, out);
}

// Round 4
// 356.471 us; speedup vs baseline: 1.2077x; 1.0994x over previous
//
#include <hip/hip_runtime.h>
#include <hip/hip_bf16.h>
#include <stdint.h>

// x: [B=16, H=224, W=224, C=64] fp32 NHWC; gating_kernel: [2,2,64,1] fp32
// conv stride 2x2 valid -> g: [16,112,112]; top-K=1254 per batch;
// gate = scatter of top-k values; out = x * gate (broadcast 2x2xC).
#define BATCH   16
#define HDIM    224
#define WDIM    224
#define CDIM    64
#define HO      112
#define WO      112
#define NPATCH  (HO * WO)        // 12544 = 256 * 49
#define KSEL    1254
#define ROWF    (WDIM * CDIM)    // 14336 floats per image row
#define PERTHR  49               // keys per thread in select
#define ROWF4   (WDIM * 16)      // 3584 float4 per image row
#define BLKROW  14               // 3584 / 256 blocks per row in apply

typedef float f32x4 __attribute__((ext_vector_type(4)));  // native vec for NT store

// ---------------------------------------------------------------------------
// Kernel 1: gating conv. One patch per half-wave; 2x128 contiguous floats per
// patch, float4 per lane -> wave-level 1KB contiguous loads. Memory-bound.
// ---------------------------------------------------------------------------
__global__ __launch_bounds__(256) void conv_gate_kernel(
    const float* __restrict__ x, const float* __restrict__ wk,
    float* __restrict__ g) {
  const int tid = threadIdx.x;
  const int lane = tid & 31;
  const int p = blockIdx.x * 8 + (tid >> 5);  // 8 half-waves/block

  const int b   = p / NPATCH;
  const int rem = p - b * NPATCH;
  const int ho  = rem / WO;
  const int wo  = rem - ho * WO;

  const float4 w0 = *reinterpret_cast<const float4*>(wk + lane * 4);
  const float4 w1 = *reinterpret_cast<const float4*>(wk + 128 + lane * 4);

  const long row0 = (long)(b * HDIM + 2 * ho) * ROWF + wo * 128 + lane * 4;
  const float4 a0 = *reinterpret_cast<const float4*>(x + row0);
  const float4 a1 = *reinterpret_cast<const float4*>(x + row0 + ROWF);

  float partial = a0.x * w0.x + a0.y * w0.y + a0.z * w0.z + a0.w * w0.w
                + a1.x * w1.x + a1.y * w1.y + a1.z * w1.z + a1.w * w1.w;

  #pragma unroll
  for (int off = 16; off > 0; off >>= 1)
    partial += __shfl_down(partial, off, 32);

  if (lane == 0) g[p] = partial;
}

// ---------------------------------------------------------------------------
// Kernel 2: exact per-batch top-K threshold via 32-step bitwise binary search
// on order-preserving uint32 keys in registers (49/thread). Stable ties.
// ---------------------------------------------------------------------------
__global__ __launch_bounds__(256) void select_kernel(
    const float* __restrict__ g, float* __restrict__ gate) {
  __shared__ int wave_cnt[4];
  __shared__ uint32_t sh_T;
  __shared__ int sh_cg;
  __shared__ int eq_list[256];
  __shared__ int eq_count;

  const int b = blockIdx.x;
  const int tid = threadIdx.x;
  const float* __restrict__ gb  = g    + b * NPATCH;
  float* __restrict__       gtb = gate + b * NPATCH;

  uint32_t key[PERTHR];
  #pragma unroll
  for (int j = 0; j < PERTHR; ++j) {
    uint32_t u = __float_as_uint(gb[tid + j * 256]);
    key[j] = (u & 0x80000000u) ? ~u : (u | 0x80000000u);  // monotone map
  }
  if (tid == 0) eq_count = 0;

  // T = max{t : count(keys >= t) >= K}, built bit by bit from the top.
  uint32_t T = 0;
  for (int bit = 31; bit >= 0; --bit) {
    const uint32_t cand = T | (1u << bit);
    int c = 0;
    #pragma unroll
    for (int j = 0; j < PERTHR; ++j) c += (key[j] >= cand) ? 1 : 0;
    #pragma unroll
    for (int off = 32; off > 0; off >>= 1) c += __shfl_down(c, off, 64);
    if ((tid & 63) == 0) wave_cnt[tid >> 6] = c;
    __syncthreads();
    if (tid == 0) {
      int tot = wave_cnt[0] + wave_cnt[1] + wave_cnt[2] + wave_cnt[3];
      sh_T = (tot >= KSEL) ? cand : T;
    }
    __syncthreads();
    T = sh_T;
  }

  {
    int c = 0;
    #pragma unroll
    for (int j = 0; j < PERTHR; ++j) c += (key[j] > T) ? 1 : 0;
    #pragma unroll
    for (int off = 32; off > 0; off >>= 1) c += __shfl_down(c, off, 64);
    if ((tid & 63) == 0) wave_cnt[tid >> 6] = c;
    __syncthreads();
    if (tid == 0) sh_cg = wave_cnt[0] + wave_cnt[1] + wave_cnt[2] + wave_cnt[3];
    __syncthreads();
  }
  const int krem = KSEL - sh_cg;  // threshold-equal elements to keep

  #pragma unroll
  for (int j = 0; j < PERTHR; ++j) {
    const int i = tid + j * 256;
    const uint32_t k = key[j];
    float v = 0.0f;
    if (k > T) {
      uint32_t u = (k & 0x80000000u) ? (k & 0x7FFFFFFFu) : ~k;
      v = __uint_as_float(u);
    }
    gtb[i] = v;
    if (k == T) {
      int pos = atomicAdd(&eq_count, 1);
      if (pos < 256) eq_list[pos] = i;
    }
  }
  __syncthreads();

  if (tid == 0) {
    const int ec = eq_count;
    if (ec <= 256) {
      for (int i = 0; i < ec; ++i) {          // sort tiny tie list by index
        int mn = i;
        for (int j = i + 1; j < ec; ++j)
          if (eq_list[j] < eq_list[mn]) mn = j;
        int t = eq_list[mn]; eq_list[mn] = eq_list[i]; eq_list[i] = t;
      }
      for (int i = 0; i < ec && i < krem; ++i) {
        int idx = eq_list[i];
        uint32_t u = (T & 0x80000000u) ? (T & 0x7FFFFFFFu) : ~T;
        gtb[idx] = __uint_as_float(u);
      }
    } else {
      int kept = 0;                            // pathological mass-tie path
      for (int i = 0; i < NPATCH; ++i) {
        uint32_t u = __float_as_uint(gb[i]);
        uint32_t k = (u & 0x80000000u) ? ~u : (u | 0x80000000u);
        if (k == T) { gtb[i] = (kept < krem) ? gb[i] : 0.0f; ++kept; }
      }
    }
  }
}

// ---------------------------------------------------------------------------
// Kernel 3: SPARSE apply. 90% of patches have gate==0 -> write zeros without
// reading x (drops x-read traffic 205 MB -> ~20 MB, and that remnant should
// hit L3 since conv just streamed x). Non-temporal stores for out (write-once
// stream; keep caches for x). 32-bit index math, one block per 256-float4
// chunk of an image row: grid = B * H * 14.
// ---------------------------------------------------------------------------
__global__ __launch_bounds__(256) void apply_gate_kernel(
    const float* __restrict__ x, const float* __restrict__ gate,
    float* __restrict__ out) {
  const int bi = blockIdx.x;
  const int rowblk = bi % BLKROW;          // which 256-float4 chunk of the row
  const int rowid  = bi / BLKROW;          // global row id: b*224 + h
  const int h = rowid % HDIM;
  const int b = rowid / HDIM;

  const int v4row = rowblk * 256 + threadIdx.x;   // float4 index within row
  const int w = v4row >> 4;                       // pixel within row
  const int gidx = b * NPATCH + (h >> 1) * WO + (w >> 1);

  const float gv = gate[gidx];
  const size_t v4 = (size_t)rowid * ROWF4 + v4row;  // global float4 index

  f32x4 o = {0.0f, 0.0f, 0.0f, 0.0f};
  if (gv != 0.0f) {
    const f32x4 a = *reinterpret_cast<const f32x4*>(x + v4 * 4);
    o = a * gv;
  }
  __builtin_nontemporal_store(o, reinterpret_cast<f32x4*>(out + v4 * 4));
}

extern "C" void kernel_launch(void* const* d_in, const int* in_sizes, int n_in,
                              void* d_out, int out_size, void* d_ws, size_t ws_size,
                              hipStream_t stream) {
  const float* x  = (const float*)d_in[0];   // [16,224,224,64]
  const float* wk = (const float*)d_in[1];   // [2,2,64,1]
  float* out = (float*)d_out;

  float* g    = (float*)d_ws;                // [16, 12544]
  float* gate = g + BATCH * NPATCH;          // [16, 12544]

  conv_gate_kernel<<<(BATCH * NPATCH) / 8, 256, 0, stream>>>(x, wk, g);
  select_kernel<<<BATCH, 256, 0, stream>>>(g, gate);
  apply_gate_kernel<<<BATCH * HDIM * BLKROW, 256, 0, stream>>>(x, gate, out);
}